// Round 1
// baseline (174.320 us; speedup 1.0000x reference)
//
#include <hip/hip_runtime.h>

typedef float f32x2 __attribute__((ext_vector_type(2)));
typedef float f32x4 __attribute__((ext_vector_type(4)));

#define NLEN   8388608
#define KTAPS  257
#define MPAD   256
#define OUTLEN (NLEN + MPAD)
#define TPB    256
#define RPT    8
#define TILE   (TPB * RPT)          /* 2048 outputs per block */
#define WQ     1160                 /* float4 slots in LDS x window (>= 1156, mult of 8) */
#define NBLK   ((OUTLEN + TILE - 1) / TILE)   /* 4097 */

__device__ __forceinline__ int swz(int q) { return q ^ ((q >> 3) & 7); }

__global__ __launch_bounds__(TPB) void cconv_pk(
    const float* __restrict__ xr, const float* __restrict__ xi,
    const float* __restrict__ wr, const float* __restrict__ wi,
    float* __restrict__ out)
{
    __shared__ f32x4 lxy[WQ];       /* (xr,xi,xr,xi) pairs, swizzled at f4 granularity */
    __shared__ f32x2 pwr[264];      /* (w_r[k], w_r[k]) duplicated pairs */
    __shared__ f32x2 pwi[264];

    const int tid   = threadIdx.x;
    const int tile0 = blockIdx.x * TILE;
    const int b0    = tile0 - MPAD;          /* x index at window position p=0 */

    /* ---- stage weights (duplicated pairs, zero-padded to 264) ---- */
    for (int k = tid; k < 264; k += TPB) {
        float a = (k < KTAPS) ? wr[k] : 0.0f;
        float b = (k < KTAPS) ? wi[k] : 0.0f;
        f32x2 va; va[0] = a; va[1] = a;
        f32x2 vb; vb[0] = b; vb[1] = b;
        pwr[k] = va; pwi[k] = vb;
    }

    /* ---- stage x interleaved, swizzled ---- */
    const bool interior = (b0 >= 0) && (b0 + 2 * WQ <= NLEN);
    if (interior) {
        for (int q = tid; q < WQ; q += TPB) {
            const int g = b0 + 2 * q;
            f32x2 ar = *(const f32x2*)(xr + g);
            f32x2 ai = *(const f32x2*)(xi + g);
            f32x4 v; v[0] = ar[0]; v[1] = ai[0]; v[2] = ar[1]; v[3] = ai[1];
            lxy[swz(q)] = v;
        }
    } else {
        for (int q = tid; q < WQ; q += TPB) {
            const int g = b0 + 2 * q;
            float a0 = 0.f, i0 = 0.f, a1 = 0.f, i1 = 0.f;
            if (g >= 0 && g < NLEN)         { a0 = xr[g];     i0 = xi[g];     }
            if (g + 1 >= 0 && g + 1 < NLEN) { a1 = xr[g + 1]; i1 = xi[g + 1]; }
            f32x4 v; v[0] = a0; v[1] = i0; v[2] = a1; v[3] = i1;
            lxy[swz(q)] = v;
        }
    }
    __syncthreads();

    /* ---- accumulators: P = sum x*(wr,wr), Q = sum x*(wi,wi), x = (xr,xi) ---- */
    f32x2 P[RPT], Q[RPT];
    #pragma unroll
    for (int j = 0; j < RPT; ++j) {
        f32x2 zz; zz[0] = 0.f; zz[1] = 0.f;
        P[j] = zz; Q[j] = zz;
    }

    /* register sliding window: 16 float2 (= 8 float4 slots), period-2 refill */
    f32x4 S[8];
    const int qb = tid * 4;                  /* float4 index of window p = 8*tid */
    #pragma unroll
    for (int u = 0; u < 8; ++u) S[u] = lxy[swz(qb + u)];

#define SUBSTEP(D, PAR)                                                          \
    {                                                                            \
        const f32x2 wva = pwr[kb + (D)];                                         \
        const f32x2 wvb = pwi[kb + (D)];                                         \
        _Pragma("unroll")                                                        \
        for (int j = 0; j < RPT; ++j) {                                          \
            const int s2 = ((D) + j + (PAR) * 8) & 15;                           \
            const f32x4 v = S[s2 >> 1];                                          \
            const f32x2 x2 = (s2 & 1) ? __builtin_shufflevector(v, v, 2, 3)      \
                                      : __builtin_shufflevector(v, v, 0, 1);     \
            P[j] += x2 * wva;                                                    \
            Q[j] += x2 * wvb;                                                    \
        }                                                                        \
    }

#define PHASE(PAR)                                                               \
    {                                                                            \
        SUBSTEP(0, PAR) SUBSTEP(1, PAR) SUBSTEP(2, PAR) SUBSTEP(3, PAR)          \
        SUBSTEP(4, PAR) SUBSTEP(5, PAR) SUBSTEP(6, PAR) SUBSTEP(7, PAR)          \
        const int qn = qb + 8 + (kb >> 1);                                       \
        _Pragma("unroll")                                                        \
        for (int u = 0; u < 4; ++u)                                              \
            S[((PAR) ? 4 : 0) + u] = lxy[swz(qn + u)];                           \
        kb += 8;                                                                 \
    }

    int kb = 0;
    for (int ii = 0; ii < 16; ++ii) {       /* 32 phases: k = 0..255 */
        PHASE(0)
        PHASE(1)
    }

    /* tail tap k = 256: window slot (256+j)&15 = j */
    {
        const f32x2 wva = pwr[256];
        const f32x2 wvb = pwi[256];
        #pragma unroll
        for (int j = 0; j < RPT; ++j) {
            const int s2 = j;
            const f32x4 v = S[s2 >> 1];
            const f32x2 x2 = (s2 & 1) ? __builtin_shufflevector(v, v, 2, 3)
                                      : __builtin_shufflevector(v, v, 0, 1);
            P[j] += x2 * wva;
            Q[j] += x2 * wvb;
        }
    }

    /* ---- epilogue: y_r = P.x - Q.y ; y_i = P.y + Q.x ---- */
    const int m0 = tile0 + tid * RPT;
    float y[RPT], z[RPT];
    #pragma unroll
    for (int j = 0; j < RPT; ++j) {
        y[j] = P[j][0] - Q[j][1];
        z[j] = P[j][1] + Q[j][0];
    }
    if (m0 + RPT <= OUTLEN) {
        f32x4 a; a[0] = y[0]; a[1] = y[1]; a[2] = y[2]; a[3] = y[3];
        f32x4 b; b[0] = y[4]; b[1] = y[5]; b[2] = y[6]; b[3] = y[7];
        f32x4 c; c[0] = z[0]; c[1] = z[1]; c[2] = z[2]; c[3] = z[3];
        f32x4 d; d[0] = z[4]; d[1] = z[5]; d[2] = z[6]; d[3] = z[7];
        *(f32x4*)(out + m0)              = a;
        *(f32x4*)(out + m0 + 4)          = b;
        *(f32x4*)(out + OUTLEN + m0)     = c;
        *(f32x4*)(out + OUTLEN + m0 + 4) = d;
    } else {
        for (int j = 0; j < RPT; ++j) {
            if (m0 + j < OUTLEN) {
                out[m0 + j]          = y[j];
                out[OUTLEN + m0 + j] = z[j];
            }
        }
    }
}

extern "C" void kernel_launch(void* const* d_in, const int* in_sizes, int n_in,
                              void* d_out, int out_size, void* d_ws, size_t ws_size,
                              hipStream_t stream) {
    const float* xr = (const float*)d_in[0];
    const float* xi = (const float*)d_in[1];
    const float* wr = (const float*)d_in[2];
    const float* wi = (const float*)d_in[3];
    float* o = (float*)d_out;
    cconv_pk<<<NBLK, TPB, 0, stream>>>(xr, xi, wr, wi, o);
}